// Round 18
// baseline (402.972 us; speedup 1.0000x reference)
//
#include <hip/hip_runtime.h>
#include <hip/hip_bf16.h>
#include <hip/hip_fp16.h>

// N = 100000 nodes, D = 64 features, E = 1250000 edges.
// Inputs: old_g[N,D] f32, W[D,D] f32, edge_weight[E,1] f32,
//         history_db[N,D] f32, src[E] i32, dst[E] i32
// Output: concat(nodes_new[N,D], history_new[N,D]) f32.
//
// Pipeline (5 dispatches):
//  (1) fused gemm+hist: LDS-tiled fp32 GEMM h = old_g @ W (fp16 out)
//      + grid-stride single-scan dst histogram (independent work overlaps);
//  (2) scan_all: one-block exclusive scan of cnt -> offsets/cursor;
//  (3) fill: XCD-partitioned scatter of packed uint32 {src:17|wq:15};
//  (4) node kernel (R11 form): wave = 4 edge-slots x 16 feature-groups,
//      coalesced srcw chunk load + shfl broadcast, 2 gathers in flight,
//      sign-free tanh, shfl_xor slot-reduce, fused history output.

#define D_FEAT 64
#define NPART 8           // = #XCDs; blockIdx%8 ~ XCD (round-robin dispatch)
#define WQ_SCALE 32767.0f
#define WQ_INV   (1.0f / 32767.0f)

// ---------------------------------------------------------------------------
// K1: h = old_g @ W (128-row x 64-col tile per 256-thr block) + fused
// grid-stride histogram of dst (single scan, device-scope int atomics).
// ---------------------------------------------------------------------------
#define GR 128
#define GPAD 66

__global__ __launch_bounds__(256) void gemm_hist_kernel(
    const float* __restrict__ g, const float* __restrict__ W,
    __half* __restrict__ h16, int N,
    const int* __restrict__ dst, int* __restrict__ cnt, int E) {
    __shared__ float Wl[D_FEAT * D_FEAT];
    __shared__ float Gl[GR][GPAD];

    const int tid = threadIdx.x;

    {
        const float4* w4 = reinterpret_cast<const float4*>(W);
        float4* wl4 = reinterpret_cast<float4*>(Wl);
        for (int i = tid; i < D_FEAT * D_FEAT / 4; i += 256) wl4[i] = w4[i];
    }

    const int row0  = blockIdx.x * GR;
    const int nrows = min(GR, N - row0);

    for (int i = tid; i < GR * 16; i += 256) {
        const int r  = i >> 4;
        const int c4 = i & 15;
        if (r < nrows) {
            float4 v = reinterpret_cast<const float4*>(
                           g + (size_t)(row0 + r) * D_FEAT)[c4];
            float* dp = &Gl[r][c4 * 4];
            reinterpret_cast<float2*>(dp)[0] = make_float2(v.x, v.y);
            reinterpret_cast<float2*>(dp)[1] = make_float2(v.z, v.w);
        }
    }
    __syncthreads();

    const int cg = tid & 7;
    const int rg = tid >> 3;
    const int c0 = cg * 8;
    const int r0 = rg * 4;

    float acc[4][8];
#pragma unroll
    for (int i = 0; i < 4; ++i)
#pragma unroll
        for (int j = 0; j < 8; ++j) acc[i][j] = 0.0f;

#pragma unroll 4
    for (int k = 0; k < D_FEAT; ++k) {
        const float4 wa = *reinterpret_cast<const float4*>(&Wl[k * D_FEAT + c0]);
        const float4 wb = *reinterpret_cast<const float4*>(&Wl[k * D_FEAT + c0 + 4]);
        float gv[4];
#pragma unroll
        for (int i = 0; i < 4; ++i) gv[i] = Gl[r0 + i][k];
#pragma unroll
        for (int i = 0; i < 4; ++i) {
            acc[i][0] = fmaf(gv[i], wa.x, acc[i][0]);
            acc[i][1] = fmaf(gv[i], wa.y, acc[i][1]);
            acc[i][2] = fmaf(gv[i], wa.z, acc[i][2]);
            acc[i][3] = fmaf(gv[i], wa.w, acc[i][3]);
            acc[i][4] = fmaf(gv[i], wb.x, acc[i][4]);
            acc[i][5] = fmaf(gv[i], wb.y, acc[i][5]);
            acc[i][6] = fmaf(gv[i], wb.z, acc[i][6]);
            acc[i][7] = fmaf(gv[i], wb.w, acc[i][7]);
        }
    }

#pragma unroll
    for (int i = 0; i < 4; ++i) {
        const int r = r0 + i;
        if (r < nrows) {
            __half2 hb[4];
#pragma unroll
            for (int j = 0; j < 4; ++j)
                hb[j] = __floats2half2_rn(acc[i][2 * j], acc[i][2 * j + 1]);
            *reinterpret_cast<uint4*>(h16 + (size_t)(row0 + r) * D_FEAT + c0) =
                *reinterpret_cast<uint4*>(hb);
        }
    }

    // ---- fused histogram (independent of the GEMM work above) ----
    const int gtid = blockIdx.x * 256 + tid;
    const int gstride = gridDim.x * 256;
    const int E4 = E >> 2;
    const int4* dst4 = reinterpret_cast<const int4*>(dst);
    for (int i = gtid; i < E4; i += gstride) {
        int4 d = dst4[i];
        atomicAdd(&cnt[d.x], 1);
        atomicAdd(&cnt[d.y], 1);
        atomicAdd(&cnt[d.z], 1);
        atomicAdd(&cnt[d.w], 1);
    }
    for (int e = E4 * 4 + gtid; e < E; e += gstride)
        atomicAdd(&cnt[dst[e]], 1);
}

// ---------------------------------------------------------------------------
// K2: one-block exclusive scan of cnt[n] -> offsets[n+1], cursor[n].
// ---------------------------------------------------------------------------
__global__ __launch_bounds__(1024) void scan_all_kernel(
    const int* __restrict__ cnt, int* __restrict__ offsets,
    int* __restrict__ cursor, int n, int E) {
    __shared__ int lds[1024];
    const int t = threadIdx.x;
    const int chunk = (n + 1023) >> 10;
    const int lo = t * chunk;
    const int hi = min(lo + chunk, n);

    int s = 0;
    for (int i = lo; i < hi; ++i) s += cnt[i];
    lds[t] = s;
    __syncthreads();
    for (int off = 1; off < 1024; off <<= 1) {
        int x = (t >= off) ? lds[t - off] : 0;
        __syncthreads();
        lds[t] += x;
        __syncthreads();
    }
    int run = lds[t] - s;   // exclusive prefix
    for (int i = lo; i < hi; ++i) {
        int v = cnt[i];
        offsets[i] = run;
        cursor[i]  = run;
        run += v;
    }
    if (t == 1023) offsets[n] = E;
}

// ---------------------------------------------------------------------------
// K3: fill — XCD-partitioned scatter of packed payload.
// ---------------------------------------------------------------------------
__device__ __forceinline__ unsigned pack_edge(int s, float w) {
    int wq = __float2int_rn(w * WQ_SCALE);
    wq = min(wq, 32767);
    wq = max(wq, 0);
    return (unsigned)s | ((unsigned)wq << 17);
}

__global__ void fill_kernel(const int* __restrict__ src,
                            const int* __restrict__ dst,
                            const float* __restrict__ ew,
                            int* __restrict__ cursor,
                            unsigned* __restrict__ srcw, int E, int npp) {
    const int part = blockIdx.x & (NPART - 1);
    const int lo = part * npp;
    const int hi = lo + npp;
    const int bid = blockIdx.x >> 3;
    const int nb  = gridDim.x >> 3;
    const int E4 = E >> 2;
    const int4* dst4 = reinterpret_cast<const int4*>(dst);

    int i = bid * blockDim.x + threadIdx.x;
    const int stride = nb * blockDim.x;
    for (; i < E4; i += stride) {
        int4 d = dst4[i];
        const int e = i * 4;
        if (d.x >= lo && d.x < hi) {
            int pos = atomicAdd(&cursor[d.x], 1);
            srcw[pos] = pack_edge(src[e + 0], ew[e + 0]);
        }
        if (d.y >= lo && d.y < hi) {
            int pos = atomicAdd(&cursor[d.y], 1);
            srcw[pos] = pack_edge(src[e + 1], ew[e + 1]);
        }
        if (d.z >= lo && d.z < hi) {
            int pos = atomicAdd(&cursor[d.z], 1);
            srcw[pos] = pack_edge(src[e + 2], ew[e + 2]);
        }
        if (d.w >= lo && d.w < hi) {
            int pos = atomicAdd(&cursor[d.w], 1);
            srcw[pos] = pack_edge(src[e + 3], ew[e + 3]);
        }
    }
    for (int e = E4 * 4 + bid * blockDim.x + threadIdx.x; e < E;
         e += nb * blockDim.x) {
        int d = dst[e];
        if (d >= lo && d < hi) {
            int pos = atomicAdd(&cursor[d], 1);
            srcw[pos] = pack_edge(src[e], ew[e]);
        }
    }
}

// ---------------------------------------------------------------------------
// K4: node kernel (R11 form) with sign-free tanh.
// ---------------------------------------------------------------------------
__device__ __forceinline__ float fast_tanh(float x) {
    float e = __builtin_amdgcn_exp2f(2.885390082f * x);   // e^{2x}
    float r = __builtin_amdgcn_rcpf(1.0f + e);
    return fmaf(-2.0f, r, 1.0f);                          // (e-1)/(e+1)
}

__global__ void node_kernel(const __half* __restrict__ h16,
                            const float* __restrict__ g,
                            const float* __restrict__ hist,
                            const int* __restrict__ offsets,
                            const unsigned* __restrict__ srcw,
                            float* __restrict__ out_nodes,
                            float* __restrict__ out_hist, int N) {
    const int lane = threadIdx.x & 63;
    const int wid  = threadIdx.x >> 6;
    const int wpb  = blockDim.x >> 6;
    const int slot = lane >> 4;      // 0..3: edge within group of 4
    const int fg   = lane & 15;      // feature group: floats fg*4 .. fg*4+3

    for (int n = blockIdx.x * wpb + wid; n < N; n += gridDim.x * wpb) {
        const int beg = offsets[n];
        const int end = offsets[n + 1];
        const float4 gd = *reinterpret_cast<const float4*>(
            g + (size_t)n * D_FEAT + fg * 4);

        float4 acc = make_float4(0.0f, 0.0f, 0.0f, 0.0f);

        for (int base = beg; base < end; base += 64) {
            const int chunk = min(64, end - base);
            const unsigned my_sw = srcw[base + min(lane, chunk - 1)];

            for (int g0 = 0; g0 < chunk; g0 += 8) {
                const int ia = g0 + slot;
                const int ib = ia + 4;
                const unsigned pa = (unsigned)__shfl((int)my_sw, ia, 64);
                const unsigned pb = (unsigned)__shfl((int)my_sw, ib, 64);
                const int   sa = pa & 0x1FFFF;
                const float wa = (float)(pa >> 17) * WQ_INV;
                const int   sb = pb & 0x1FFFF;
                const float wb = (float)(pb >> 17) * WQ_INV;
                const bool va = ia < chunk;
                const bool vb = ib < chunk;
                // both gathers issued before either consumed
                const uint2 hva = *reinterpret_cast<const uint2*>(
                    h16 + (size_t)sa * D_FEAT + fg * 4);
                const uint2 hvb = *reinterpret_cast<const uint2*>(
                    h16 + (size_t)sb * D_FEAT + fg * 4);

                const float2 a0 = __half22float2(
                    *reinterpret_cast<const __half2*>(&hva.x));
                const float2 a1 = __half22float2(
                    *reinterpret_cast<const __half2*>(&hva.y));
                const float ma = va ? 1.0f : 0.0f;
                acc.x = fmaf(ma, fast_tanh(fmaf(gd.x, wa, a0.x)), acc.x);
                acc.y = fmaf(ma, fast_tanh(fmaf(gd.y, wa, a0.y)), acc.y);
                acc.z = fmaf(ma, fast_tanh(fmaf(gd.z, wa, a1.x)), acc.z);
                acc.w = fmaf(ma, fast_tanh(fmaf(gd.w, wa, a1.y)), acc.w);

                const float2 b0 = __half22float2(
                    *reinterpret_cast<const __half2*>(&hvb.x));
                const float2 b1 = __half22float2(
                    *reinterpret_cast<const __half2*>(&hvb.y));
                const float mb = vb ? 1.0f : 0.0f;
                acc.x = fmaf(mb, fast_tanh(fmaf(gd.x, wb, b0.x)), acc.x);
                acc.y = fmaf(mb, fast_tanh(fmaf(gd.y, wb, b0.y)), acc.y);
                acc.z = fmaf(mb, fast_tanh(fmaf(gd.z, wb, b1.x)), acc.z);
                acc.w = fmaf(mb, fast_tanh(fmaf(gd.w, wb, b1.y)), acc.w);
            }
        }

        // combine the 4 slots (lanes differing in bits 4 and 5)
        acc.x += __shfl_xor(acc.x, 16, 64);
        acc.y += __shfl_xor(acc.y, 16, 64);
        acc.z += __shfl_xor(acc.z, 16, 64);
        acc.w += __shfl_xor(acc.w, 16, 64);
        acc.x += __shfl_xor(acc.x, 32, 64);
        acc.y += __shfl_xor(acc.y, 32, 64);
        acc.z += __shfl_xor(acc.z, 32, 64);
        acc.w += __shfl_xor(acc.w, 32, 64);

        if (lane < 16) {
            const float4 hv4 = *reinterpret_cast<const float4*>(
                hist + (size_t)n * D_FEAT + fg * 4);
            reinterpret_cast<float4*>(out_nodes + (size_t)n * D_FEAT)[fg] = acc;
            float4 o;
            o.x = acc.x + hv4.x;
            o.y = acc.y + hv4.y;
            o.z = acc.z + hv4.z;
            o.w = acc.w + hv4.w;
            reinterpret_cast<float4*>(out_hist + (size_t)n * D_FEAT)[fg] = o;
        }
    }
}

extern "C" void kernel_launch(void* const* d_in, const int* in_sizes, int n_in,
                              void* d_out, int out_size, void* d_ws, size_t ws_size,
                              hipStream_t stream) {
    const float* old_g = (const float*)d_in[0];
    const float* W     = (const float*)d_in[1];
    const float* ew    = (const float*)d_in[2];
    const float* hist  = (const float*)d_in[3];
    const int*   src   = (const int*)d_in[4];
    const int*   dst   = (const int*)d_in[5];

    const int N  = in_sizes[0] / D_FEAT;
    const int E  = in_sizes[4];
    const int ND = N * D_FEAT;
    const int npp = (N + NPART - 1) / NPART;

    float* out_nodes = (float*)d_out;
    float* out_hist  = (float*)d_out + ND;

    // Workspace layout
    char* ws = (char*)d_ws;
    __half* h16     = (__half*)ws;                     ws += (size_t)ND * 2;
    int*   cnt      = (int*)ws;                        ws += (size_t)N * 4;
    int*   offsets  = (int*)ws;                        ws += (size_t)(N + 2) * 4;
    int*   cursor   = (int*)ws;                        ws += (size_t)N * 4;
    unsigned* srcw  = (unsigned*)ws;                   // E entries (4B each)

    hipMemsetAsync(cnt, 0, (size_t)N * sizeof(int), stream);

    // K1: fused GEMM (fp16 out) + single-scan histogram
    {
        int grid = (N + GR - 1) / GR;
        gemm_hist_kernel<<<grid, 256, 0, stream>>>(old_g, W, h16, N,
                                                   dst, cnt, E);
    }

    // K2: one-block scan -> offsets/cursor
    scan_all_kernel<<<1, 1024, 0, stream>>>(cnt, offsets, cursor, N, E);

    // K3: XCD-partitioned fill (packed payload)
    fill_kernel<<<2048, 256, 0, stream>>>(src, dst, ew, cursor, srcw, E, npp);

    // K4: per-node accumulation + fused history
    {
        const int block = 256, wpb = block / 64;
        int grid = (N + wpb - 1) / wpb;
        if (grid > 8192) grid = 8192;
        node_kernel<<<grid, block, 0, stream>>>(h16, old_g, hist, offsets, srcw,
                                                out_nodes, out_hist, N);
    }
}

// Round 19
// 196.165 us; speedup vs baseline: 2.0542x; 2.0542x over previous
//
#include <hip/hip_runtime.h>
#include <hip/hip_bf16.h>
#include <hip/hip_fp16.h>

// N = 100000 nodes, D = 64 features, E = 1250000 edges.
// Inputs: old_g[N,D] f32, W[D,D] f32, edge_weight[E,1] f32,
//         history_db[N,D] f32, src[E] i32, dst[E] i32
// Output: concat(nodes_new[N,D], history_new[N,D]) f32.
//
// Pipeline (7 dispatches):
//  (1) fused gemm+hist: LDS-tiled fp32 GEMM h = old_g @ W (fp16 out)
//      + grid-stride single-scan dst histogram;
//  (2) 3-kernel scan (coalesced, 98 blocks): block_sum -> top_scan ->
//      scan_fill.  (R18's one-block scan_all was 233us: strided serial
//      reads on one CU -- reverted.)
//  (3) fill: XCD-partitioned scatter of packed uint32 {src:17|wq:15};
//  (4) node kernel (R11 form): wave = 4 edge-slots x 16 feature-groups,
//      coalesced srcw chunk load + shfl broadcast, 2 gathers in flight,
//      sign-free tanh, shfl_xor slot-reduce, fused history output.

#define D_FEAT 64
#define SCAN_BLK 256
#define SCAN_CHUNK 1024   // 4 elements per thread
#define NPART 8           // = #XCDs; blockIdx%8 ~ XCD (round-robin dispatch)
#define WQ_SCALE 32767.0f
#define WQ_INV   (1.0f / 32767.0f)

// ---------------------------------------------------------------------------
// K1: h = old_g @ W (128-row x 64-col tile per 256-thr block) + fused
// grid-stride histogram of dst (single scan, device-scope int atomics).
// ---------------------------------------------------------------------------
#define GR 128
#define GPAD 66

__global__ __launch_bounds__(256) void gemm_hist_kernel(
    const float* __restrict__ g, const float* __restrict__ W,
    __half* __restrict__ h16, int N,
    const int* __restrict__ dst, int* __restrict__ cnt, int E) {
    __shared__ float Wl[D_FEAT * D_FEAT];
    __shared__ float Gl[GR][GPAD];

    const int tid = threadIdx.x;

    {
        const float4* w4 = reinterpret_cast<const float4*>(W);
        float4* wl4 = reinterpret_cast<float4*>(Wl);
        for (int i = tid; i < D_FEAT * D_FEAT / 4; i += 256) wl4[i] = w4[i];
    }

    const int row0  = blockIdx.x * GR;
    const int nrows = min(GR, N - row0);

    for (int i = tid; i < GR * 16; i += 256) {
        const int r  = i >> 4;
        const int c4 = i & 15;
        if (r < nrows) {
            float4 v = reinterpret_cast<const float4*>(
                           g + (size_t)(row0 + r) * D_FEAT)[c4];
            float* dp = &Gl[r][c4 * 4];
            reinterpret_cast<float2*>(dp)[0] = make_float2(v.x, v.y);
            reinterpret_cast<float2*>(dp)[1] = make_float2(v.z, v.w);
        }
    }
    __syncthreads();

    const int cg = tid & 7;
    const int rg = tid >> 3;
    const int c0 = cg * 8;
    const int r0 = rg * 4;

    float acc[4][8];
#pragma unroll
    for (int i = 0; i < 4; ++i)
#pragma unroll
        for (int j = 0; j < 8; ++j) acc[i][j] = 0.0f;

#pragma unroll 4
    for (int k = 0; k < D_FEAT; ++k) {
        const float4 wa = *reinterpret_cast<const float4*>(&Wl[k * D_FEAT + c0]);
        const float4 wb = *reinterpret_cast<const float4*>(&Wl[k * D_FEAT + c0 + 4]);
        float gv[4];
#pragma unroll
        for (int i = 0; i < 4; ++i) gv[i] = Gl[r0 + i][k];
#pragma unroll
        for (int i = 0; i < 4; ++i) {
            acc[i][0] = fmaf(gv[i], wa.x, acc[i][0]);
            acc[i][1] = fmaf(gv[i], wa.y, acc[i][1]);
            acc[i][2] = fmaf(gv[i], wa.z, acc[i][2]);
            acc[i][3] = fmaf(gv[i], wa.w, acc[i][3]);
            acc[i][4] = fmaf(gv[i], wb.x, acc[i][4]);
            acc[i][5] = fmaf(gv[i], wb.y, acc[i][5]);
            acc[i][6] = fmaf(gv[i], wb.z, acc[i][6]);
            acc[i][7] = fmaf(gv[i], wb.w, acc[i][7]);
        }
    }

#pragma unroll
    for (int i = 0; i < 4; ++i) {
        const int r = r0 + i;
        if (r < nrows) {
            __half2 hb[4];
#pragma unroll
            for (int j = 0; j < 4; ++j)
                hb[j] = __floats2half2_rn(acc[i][2 * j], acc[i][2 * j + 1]);
            *reinterpret_cast<uint4*>(h16 + (size_t)(row0 + r) * D_FEAT + c0) =
                *reinterpret_cast<uint4*>(hb);
        }
    }

    // ---- fused histogram (independent of the GEMM work above) ----
    const int gtid = blockIdx.x * 256 + tid;
    const int gstride = gridDim.x * 256;
    const int E4 = E >> 2;
    const int4* dst4 = reinterpret_cast<const int4*>(dst);
    for (int i = gtid; i < E4; i += gstride) {
        int4 d = dst4[i];
        atomicAdd(&cnt[d.x], 1);
        atomicAdd(&cnt[d.y], 1);
        atomicAdd(&cnt[d.z], 1);
        atomicAdd(&cnt[d.w], 1);
    }
    for (int e = E4 * 4 + gtid; e < E; e += gstride)
        atomicAdd(&cnt[dst[e]], 1);
}

// ---------------------------------------------------------------------------
// 3-kernel coalesced scan: block_sum -> top_scan -> scan_fill.
// ---------------------------------------------------------------------------
__global__ void block_sum_kernel(const int* __restrict__ cnt, int n,
                                 int* __restrict__ blockSums) {
    __shared__ int lds[SCAN_BLK];
    const int base = blockIdx.x * SCAN_CHUNK;
    const int t = threadIdx.x;
    int s = 0;
#pragma unroll
    for (int i = 0; i < 4; ++i) {
        int idx = base + t * 4 + i;
        s += (idx < n) ? cnt[idx] : 0;
    }
    lds[t] = s;
    __syncthreads();
    for (int off = SCAN_BLK / 2; off > 0; off >>= 1) {
        if (t < off) lds[t] += lds[t + off];
        __syncthreads();
    }
    if (t == 0) blockSums[blockIdx.x] = lds[0];
}

__global__ void top_scan_kernel(int* __restrict__ blockSums, int nb) {
    if (threadIdx.x == 0 && blockIdx.x == 0) {
        int acc = 0;
        for (int i = 0; i < nb; ++i) {
            int v = blockSums[i];
            blockSums[i] = acc;
            acc += v;
        }
    }
}

__global__ void scan_fill_kernel(const int* __restrict__ cnt, int n,
                                 const int* __restrict__ blockSums,
                                 int* __restrict__ offsets,
                                 int* __restrict__ cursor, int E) {
    __shared__ int lds[SCAN_BLK];
    const int base = blockIdx.x * SCAN_CHUNK;
    const int t = threadIdx.x;
    int v[4];
    int s = 0;
#pragma unroll
    for (int i = 0; i < 4; ++i) {
        int idx = base + t * 4 + i;
        v[i] = (idx < n) ? cnt[idx] : 0;
        s += v[i];
    }
    lds[t] = s;
    __syncthreads();
    for (int off = 1; off < SCAN_BLK; off <<= 1) {
        int x = (t >= off) ? lds[t - off] : 0;
        __syncthreads();
        lds[t] += x;
        __syncthreads();
    }
    int run = lds[t] - s + blockSums[blockIdx.x];  // exclusive prefix
#pragma unroll
    for (int i = 0; i < 4; ++i) {
        int idx = base + t * 4 + i;
        if (idx < n) {
            offsets[idx] = run;
            cursor[idx]  = run;
            run += v[i];
        }
    }
    if (blockIdx.x == 0 && t == 0) offsets[n] = E;
}

// ---------------------------------------------------------------------------
// K3: fill — XCD-partitioned scatter of packed payload.
// ---------------------------------------------------------------------------
__device__ __forceinline__ unsigned pack_edge(int s, float w) {
    int wq = __float2int_rn(w * WQ_SCALE);
    wq = min(wq, 32767);
    wq = max(wq, 0);
    return (unsigned)s | ((unsigned)wq << 17);
}

__global__ void fill_kernel(const int* __restrict__ src,
                            const int* __restrict__ dst,
                            const float* __restrict__ ew,
                            int* __restrict__ cursor,
                            unsigned* __restrict__ srcw, int E, int npp) {
    const int part = blockIdx.x & (NPART - 1);
    const int lo = part * npp;
    const int hi = lo + npp;
    const int bid = blockIdx.x >> 3;
    const int nb  = gridDim.x >> 3;
    const int E4 = E >> 2;
    const int4* dst4 = reinterpret_cast<const int4*>(dst);

    int i = bid * blockDim.x + threadIdx.x;
    const int stride = nb * blockDim.x;
    for (; i < E4; i += stride) {
        int4 d = dst4[i];
        const int e = i * 4;
        if (d.x >= lo && d.x < hi) {
            int pos = atomicAdd(&cursor[d.x], 1);
            srcw[pos] = pack_edge(src[e + 0], ew[e + 0]);
        }
        if (d.y >= lo && d.y < hi) {
            int pos = atomicAdd(&cursor[d.y], 1);
            srcw[pos] = pack_edge(src[e + 1], ew[e + 1]);
        }
        if (d.z >= lo && d.z < hi) {
            int pos = atomicAdd(&cursor[d.z], 1);
            srcw[pos] = pack_edge(src[e + 2], ew[e + 2]);
        }
        if (d.w >= lo && d.w < hi) {
            int pos = atomicAdd(&cursor[d.w], 1);
            srcw[pos] = pack_edge(src[e + 3], ew[e + 3]);
        }
    }
    for (int e = E4 * 4 + bid * blockDim.x + threadIdx.x; e < E;
         e += nb * blockDim.x) {
        int d = dst[e];
        if (d >= lo && d < hi) {
            int pos = atomicAdd(&cursor[d], 1);
            srcw[pos] = pack_edge(src[e], ew[e]);
        }
    }
}

// ---------------------------------------------------------------------------
// K4: node kernel (R11 form) with sign-free tanh.
// ---------------------------------------------------------------------------
__device__ __forceinline__ float fast_tanh(float x) {
    float e = __builtin_amdgcn_exp2f(2.885390082f * x);   // e^{2x}
    float r = __builtin_amdgcn_rcpf(1.0f + e);
    return fmaf(-2.0f, r, 1.0f);                          // (e-1)/(e+1)
}

__global__ void node_kernel(const __half* __restrict__ h16,
                            const float* __restrict__ g,
                            const float* __restrict__ hist,
                            const int* __restrict__ offsets,
                            const unsigned* __restrict__ srcw,
                            float* __restrict__ out_nodes,
                            float* __restrict__ out_hist, int N) {
    const int lane = threadIdx.x & 63;
    const int wid  = threadIdx.x >> 6;
    const int wpb  = blockDim.x >> 6;
    const int slot = lane >> 4;      // 0..3: edge within group of 4
    const int fg   = lane & 15;      // feature group: floats fg*4 .. fg*4+3

    for (int n = blockIdx.x * wpb + wid; n < N; n += gridDim.x * wpb) {
        const int beg = offsets[n];
        const int end = offsets[n + 1];
        const float4 gd = *reinterpret_cast<const float4*>(
            g + (size_t)n * D_FEAT + fg * 4);

        float4 acc = make_float4(0.0f, 0.0f, 0.0f, 0.0f);

        for (int base = beg; base < end; base += 64) {
            const int chunk = min(64, end - base);
            const unsigned my_sw = srcw[base + min(lane, chunk - 1)];

            for (int g0 = 0; g0 < chunk; g0 += 8) {
                const int ia = g0 + slot;
                const int ib = ia + 4;
                const unsigned pa = (unsigned)__shfl((int)my_sw, ia, 64);
                const unsigned pb = (unsigned)__shfl((int)my_sw, ib, 64);
                const int   sa = pa & 0x1FFFF;
                const float wa = (float)(pa >> 17) * WQ_INV;
                const int   sb = pb & 0x1FFFF;
                const float wb = (float)(pb >> 17) * WQ_INV;
                const bool va = ia < chunk;
                const bool vb = ib < chunk;
                // both gathers issued before either consumed
                const uint2 hva = *reinterpret_cast<const uint2*>(
                    h16 + (size_t)sa * D_FEAT + fg * 4);
                const uint2 hvb = *reinterpret_cast<const uint2*>(
                    h16 + (size_t)sb * D_FEAT + fg * 4);

                const float2 a0 = __half22float2(
                    *reinterpret_cast<const __half2*>(&hva.x));
                const float2 a1 = __half22float2(
                    *reinterpret_cast<const __half2*>(&hva.y));
                const float ma = va ? 1.0f : 0.0f;
                acc.x = fmaf(ma, fast_tanh(fmaf(gd.x, wa, a0.x)), acc.x);
                acc.y = fmaf(ma, fast_tanh(fmaf(gd.y, wa, a0.y)), acc.y);
                acc.z = fmaf(ma, fast_tanh(fmaf(gd.z, wa, a1.x)), acc.z);
                acc.w = fmaf(ma, fast_tanh(fmaf(gd.w, wa, a1.y)), acc.w);

                const float2 b0 = __half22float2(
                    *reinterpret_cast<const __half2*>(&hvb.x));
                const float2 b1 = __half22float2(
                    *reinterpret_cast<const __half2*>(&hvb.y));
                const float mb = vb ? 1.0f : 0.0f;
                acc.x = fmaf(mb, fast_tanh(fmaf(gd.x, wb, b0.x)), acc.x);
                acc.y = fmaf(mb, fast_tanh(fmaf(gd.y, wb, b0.y)), acc.y);
                acc.z = fmaf(mb, fast_tanh(fmaf(gd.z, wb, b1.x)), acc.z);
                acc.w = fmaf(mb, fast_tanh(fmaf(gd.w, wb, b1.y)), acc.w);
            }
        }

        // combine the 4 slots (lanes differing in bits 4 and 5)
        acc.x += __shfl_xor(acc.x, 16, 64);
        acc.y += __shfl_xor(acc.y, 16, 64);
        acc.z += __shfl_xor(acc.z, 16, 64);
        acc.w += __shfl_xor(acc.w, 16, 64);
        acc.x += __shfl_xor(acc.x, 32, 64);
        acc.y += __shfl_xor(acc.y, 32, 64);
        acc.z += __shfl_xor(acc.z, 32, 64);
        acc.w += __shfl_xor(acc.w, 32, 64);

        if (lane < 16) {
            const float4 hv4 = *reinterpret_cast<const float4*>(
                hist + (size_t)n * D_FEAT + fg * 4);
            reinterpret_cast<float4*>(out_nodes + (size_t)n * D_FEAT)[fg] = acc;
            float4 o;
            o.x = acc.x + hv4.x;
            o.y = acc.y + hv4.y;
            o.z = acc.z + hv4.z;
            o.w = acc.w + hv4.w;
            reinterpret_cast<float4*>(out_hist + (size_t)n * D_FEAT)[fg] = o;
        }
    }
}

extern "C" void kernel_launch(void* const* d_in, const int* in_sizes, int n_in,
                              void* d_out, int out_size, void* d_ws, size_t ws_size,
                              hipStream_t stream) {
    const float* old_g = (const float*)d_in[0];
    const float* W     = (const float*)d_in[1];
    const float* ew    = (const float*)d_in[2];
    const float* hist  = (const float*)d_in[3];
    const int*   src   = (const int*)d_in[4];
    const int*   dst   = (const int*)d_in[5];

    const int N  = in_sizes[0] / D_FEAT;
    const int E  = in_sizes[4];
    const int ND = N * D_FEAT;
    const int npp = (N + NPART - 1) / NPART;

    float* out_nodes = (float*)d_out;
    float* out_hist  = (float*)d_out + ND;

    // Workspace layout
    char* ws = (char*)d_ws;
    __half* h16     = (__half*)ws;                     ws += (size_t)ND * 2;
    int*   cnt      = (int*)ws;                        ws += (size_t)N * 4;
    int*   offsets  = (int*)ws;                        ws += (size_t)(N + 2) * 4;
    int*   cursor   = (int*)ws;                        ws += (size_t)N * 4;
    int*   blockSums= (int*)ws;                        ws += 1024 * 4;
    unsigned* srcw  = (unsigned*)ws;                   // E entries (4B each)

    const int nb = (N + SCAN_CHUNK - 1) / SCAN_CHUNK;

    hipMemsetAsync(cnt, 0, (size_t)N * sizeof(int), stream);

    // K1: fused GEMM (fp16 out) + single-scan histogram
    {
        int grid = (N + GR - 1) / GR;
        gemm_hist_kernel<<<grid, 256, 0, stream>>>(old_g, W, h16, N,
                                                   dst, cnt, E);
    }

    // K2: coalesced 3-kernel scan -> offsets/cursor
    block_sum_kernel<<<nb, SCAN_BLK, 0, stream>>>(cnt, N, blockSums);
    top_scan_kernel<<<1, 64, 0, stream>>>(blockSums, nb);
    scan_fill_kernel<<<nb, SCAN_BLK, 0, stream>>>(cnt, N, blockSums, offsets,
                                                  cursor, E);

    // K3: XCD-partitioned fill (packed payload)
    fill_kernel<<<2048, 256, 0, stream>>>(src, dst, ew, cursor, srcw, E, npp);

    // K4: per-node accumulation + fused history
    {
        const int block = 256, wpb = block / 64;
        int grid = (N + wpb - 1) / wpb;
        if (grid > 8192) grid = 8192;
        node_kernel<<<grid, block, 0, stream>>>(h16, old_g, hist, offsets, srcw,
                                                out_nodes, out_hist, N);
    }
}